// Round 3
// baseline (462.854 us; speedup 1.0000x reference)
//
#include <hip/hip_runtime.h>
#include <math.h>

// Min-sum BP LDPC decoder, LDS-resident messages in VAR-ORDER layout.
// msg[4v..4v+3] holds the 4 edge messages of var v (DV=4 exactly), so the
// var phase and epilogue are aligned b128 LDS ops (conflict-free). The check
// phase addresses its (check-order contiguous) edges through precomputed
// byte offsets posbe[e] = (4*var_idx[e]+slot)*4, used directly as ds vaddrs.
// Slot order within a var = ascending edge order = reference's var_adj order,
// so the f32 sum order matches the reference bit-exactly.
//
// R2 changes vs R1:
//  - var-order msg layout: var phase 8 scattered b32 -> 2 aligned b128 per var
//  - check phase addresses via posbe (zero LDS address VALU)
//  - sign via MSB xor, min1/min2 via min/max identity (selection-exact)
//  - setup kernel additionally builds posbe + pos0 (pad publisher)

#define BLOCK 1024
#define NV    8192          // N variables
#define MC    4096          // M checks
#define NE    32768         // E edges (N * DV, DV=4)
#define VPT   (NV / BLOCK)  // 8 vars per thread
#define CPT   (MC / BLOCK)  // 4 checks per thread
#define NITER 10
#define ALPHA 0.8f
#define CLAMP 20.0f

// ws layout (ints):
#define WS_SORT0 0            // [0,MC)  : (cstart & 0xFFFF) | (deg<<16), degree-sorted
#define WS_SORTC MC           // [MC,2MC): original check index
#define WS_PAD0  (2*MC)       // [1]     : byte offset of edge 0 in var-order msg
#define WS_POSBE (2*MC + 64)  // [NE]    : per (check-order) edge byte offset

// ---------------- setup: sort checks by degree + build posbe ----------------
__global__ __launch_bounds__(BLOCK)
void setup_all(const float* __restrict__ check_mask,
               const int*   __restrict__ check_adj,
               const int*   __restrict__ var_adj,
               int max_dc, int* __restrict__ ws)
{
    __shared__ int hist[64];
    __shared__ int base[64];
    const int t = threadIdx.x;
    if (t < 64) hist[t] = 0;
    __syncthreads();

    int deg[CPT], cst[CPT];
#pragma unroll
    for (int k = 0; k < CPT; ++k) {
        const int c = t + k * BLOCK;
        int d = 0;
        for (int j = 0; j < max_dc; ++j)
            d += (check_mask[(size_t)c * max_dc + j] != 0.0f) ? 1 : 0;
        deg[k] = d;
        cst[k] = check_adj[(size_t)c * max_dc];  // row start (edges sorted by check)
        atomicAdd(&hist[d & 63], 1);
    }
    __syncthreads();
    if (t == 0) {
        int s = 0;
        for (int i = 0; i < 64; ++i) { base[i] = s; s += hist[i]; }
    }
    __syncthreads();
#pragma unroll
    for (int k = 0; k < CPT; ++k) {
        const int c   = t + k * BLOCK;
        const int pos = atomicAdd(&base[deg[k] & 63], 1);
        ws[WS_SORT0 + pos] = (cst[k] & 0xFFFF) | (deg[k] << 16);
        ws[WS_SORTC + pos] = c;
    }

    // posbe: var v's j-th edge (ascending edge id, = var_adj row order) lives
    // at var-order word 4v+j -> byte offset (4v+j)*4
#pragma unroll
    for (int k = 0; k < VPT; ++k) {
        const int v = t + k * BLOCK;
        const int4 a = ((const int4*)var_adj)[v];
        ws[WS_POSBE + a.x] = (4 * v + 0) * 4;
        ws[WS_POSBE + a.y] = (4 * v + 1) * 4;
        ws[WS_POSBE + a.z] = (4 * v + 2) * 4;
        ws[WS_POSBE + a.w] = (4 * v + 3) * 4;
    }
    __syncthreads();
    if (t == 0) ws[WS_PAD0] = ws[WS_POSBE + 0];   // edge 0's var-order byte offset
}

__device__ __forceinline__ float lds_ldf(const float* msg, int boff) {
    return *reinterpret_cast<const float*>(reinterpret_cast<const char*>(msg) + boff);
}
__device__ __forceinline__ void lds_stf(float* msg, int boff, float v) {
    *reinterpret_cast<float*>(reinterpret_cast<char*>(msg) + boff) = v;
}

// Single-pass check update; pos + values cached in registers (ladder-unrolled).
template<int DMAX>
__device__ __forceinline__ void do_check(float* __restrict__ msg,
                                         const int* __restrict__ pose,
                                         int d, int sb, float pad)
{
    int   p[DMAX];
    float x[DMAX];
#pragma unroll
    for (int j = 0; j < DMAX; ++j) { if (j >= d) break; p[j] = pose[j]; }
#pragma unroll
    for (int j = 0; j < DMAX; ++j) { if (j >= d) break; x[j] = lds_ldf(msg, p[j]); }

    float min1 = pad, min2 = pad;
    unsigned par = 0;
#pragma unroll
    for (int j = 0; j < DMAX; ++j) {
        if (j >= d) break;
        par ^= __float_as_uint(x[j]);                  // MSB accumulates sign parity
        const float a = fabsf(x[j]);
        min2 = fminf(min2, fmaxf(min1, a));            // two smallest, dup-exact
        min1 = fminf(min1, a);
    }
    const unsigned tb = ((unsigned)sb << 31) ^ (par & 0x80000000u);
#pragma unroll
    for (int j = 0; j < DMAX; ++j) {
        if (j >= d) break;
        const float a = fabsf(x[j]);
        const float m = (fabsf(a - min1) < 1e-9f) ? min2 : min1;   // ref tolerance
        const unsigned sm = tb ^ (__float_as_uint(x[j]) & 0x80000000u);
        lds_stf(msg, p[j], __uint_as_float(__float_as_uint(ALPHA * m) ^ sm));
    }
}

// Fallback for d > 16 (rare): re-reads LDS instead of caching.
__device__ __forceinline__ void do_check_big(float* __restrict__ msg,
                                             const int* __restrict__ pose,
                                             int d, int sb, float pad)
{
    float min1 = pad, min2 = pad;
    unsigned par = 0;
    for (int j = 0; j < d; ++j) {
        const float xx = lds_ldf(msg, pose[j]);
        par ^= __float_as_uint(xx);
        const float a = fabsf(xx);
        min2 = fminf(min2, fmaxf(min1, a));
        min1 = fminf(min1, a);
    }
    const unsigned tb = ((unsigned)sb << 31) ^ (par & 0x80000000u);
    for (int j = 0; j < d; ++j) {
        const int   p  = pose[j];
        const float xx = lds_ldf(msg, p);
        const float a  = fabsf(xx);
        const float m  = (fabsf(a - min1) < 1e-9f) ? min2 : min1;
        const unsigned sm = tb ^ (__float_as_uint(xx) & 0x80000000u);
        lds_stf(msg, p, __uint_as_float(__float_as_uint(ALPHA * m) ^ sm));
    }
}

__global__ __launch_bounds__(BLOCK)
void bp_decode(const float* __restrict__ syndrome,    // (B, M)
               const float* __restrict__ llr_g,       // (B, N)
               const int*   __restrict__ ws,          // sorted checks + posbe
               float* __restrict__ out,               // marginals | hard | converged
               int B)
{
    __shared__ float msg[NE];   // 128 KB, var-order; ctv <-> vtc in place
    __shared__ float sh_pad;
    __shared__ int   mism;

    const int b = blockIdx.x;
    const int t = threadIdx.x;

#pragma unroll
    for (int k = 0; k < VPT; ++k)                     // ctv0 = 0
        ((float4*)msg)[t + k * BLOCK] = make_float4(0.f, 0.f, 0.f, 0.f);

    float llr[VPT];
#pragma unroll
    for (int k = 0; k < VPT; ++k)
        llr[k] = llr_g[(size_t)b * NV + t + k * BLOCK];

    const int pos0 = ws[WS_PAD0];
    const int v0   = pos0 >> 4;          // owning var of edge 0
    const int s0   = (pos0 >> 2) & 3;    // its slot

    int st[CPT], dsb[CPT];               // dsb = (deg<<1) | syndrome_bit
#pragma unroll
    for (int k = 0; k < CPT; ++k) {
        const int i = t + k * BLOCK;
        const int w = ws[WS_SORT0 + i];
        const int c = ws[WS_SORTC + i];
        st[k] = w & 0xFFFF;
        const int d  = w >> 16;
        const int sb = (syndrome[(size_t)b * MC + c] > 0.5f) ? 1 : 0;
        dsb[k] = (d << 1) | sb;
    }
    const int* __restrict__ posbe = ws + WS_POSBE;
    __syncthreads();

    for (int it = 0; it < NITER; ++it) {
        // ---- variable phase: b128 in, b128 out, conflict-free ----
#pragma unroll
        for (int k = 0; k < VPT; ++k) {
            const int v = t + k * BLOCK;
            const float4 f = ((const float4*)msg)[v];
            const float tot  = ((f.x + f.y) + f.z) + f.w;   // reference sum order
            const float base = llr[k] + tot;
            float4 o;
            o.x = fminf(fmaxf(base - f.x, -CLAMP), CLAMP);
            o.y = fminf(fmaxf(base - f.y, -CLAMP), CLAMP);
            o.z = fminf(fmaxf(base - f.z, -CLAMP), CLAMP);
            o.w = fminf(fmaxf(base - f.w, -CLAMP), CLAMP);
            if (v == v0) {   // publish reference's pad = |vtc[edge0]| + 1e6
                float vt = o.x;
                if (s0 == 1) vt = o.y; else if (s0 == 2) vt = o.z; else if (s0 == 3) vt = o.w;
                sh_pad = fabsf(vt) + 1.0e6f;
            }
            ((float4*)msg)[v] = o;
        }
        __syncthreads();
        const float pad = sh_pad;

        // ---- check phase: scattered b32 via precomputed byte offsets ----
#pragma unroll
        for (int k = 0; k < CPT; ++k) {
            const int d  = dsb[k] >> 1;
            const int sb = dsb[k] & 1;
            const int* pose = posbe + st[k];
            if (d <= 8)       do_check<8>(msg, pose, d, sb, pad);
            else if (d <= 16) do_check<16>(msg, pose, d, sb, pad);
            else              do_check_big(msg, pose, d, sb, pad);
        }
        __syncthreads();
    }

    // ---- finale: marginals, hard decisions, convergence ----
    float marg[VPT], hard[VPT];
#pragma unroll
    for (int k = 0; k < VPT; ++k) {
        const int v = t + k * BLOCK;
        const float4 f = ((const float4*)msg)[v];
        const float tot = ((f.x + f.y) + f.z) + f.w;
        const float tl  = llr[k] + tot;
        const float mg  = 1.0f / (1.0f + expf(tl));   // sigmoid(-tl)
        marg[k] = mg;
        hard[k] = (mg > 0.5f) ? 1.0f : 0.0f;
    }
    if (t == 0) mism = 0;
    __syncthreads();   // all ctv reads done; mism initialized

    const size_t BN = (size_t)B * NV;
#pragma unroll
    for (int k = 0; k < VPT; ++k) {
        const int v = t + k * BLOCK;
        out[(size_t)b * NV + v]      = marg[k];        // output 0: marginals
        out[BN + (size_t)b * NV + v] = hard[k];        // output 1: hard_decision
        const float h = hard[k];
        ((float4*)msg)[v] = make_float4(h, h, h, h);   // hard bit to all 4 slots
    }
    __syncthreads();

    // syn_hat parity per check over its vars' hard bits; converged iff == syndrome
#pragma unroll
    for (int k = 0; k < CPT; ++k) {
        const int d  = dsb[k] >> 1;
        const int sb = dsb[k] & 1;
        const int* pose = posbe + st[k];
        int par = 0;
        for (int j = 0; j < d; ++j)
            par ^= (lds_ldf(msg, pose[j]) != 0.0f) ? 1 : 0;
        if (par != sb) mism = 1;   // benign race: all writers store 1
    }
    __syncthreads();
    if (t == 0) out[2 * BN + b] = mism ? 0.0f : 1.0f;  // output 2: converged
}

extern "C" void kernel_launch(void* const* d_in, const int* in_sizes, int n_in,
                              void* d_out, int out_size, void* d_ws, size_t ws_size,
                              hipStream_t stream) {
    const float* syndrome   = (const float*)d_in[0];
    const float* llr        = (const float*)d_in[1];
    const int*   var_adj    = (const int*)d_in[2];
    // d_in[3] var_adj_mask: all ones (DV=4 exact) — unused
    const int*   check_adj  = (const int*)d_in[4];
    const float* check_mask = (const float*)d_in[5];
    // d_in[6] var_idx — implicit in posbe; unused
    // d_in[7] pcm_dense — unused
    float* out = (float*)d_out;
    int*   ws  = (int*)d_ws;    // needs (2*MC + 64 + NE) ints ~= 164 KB

    const int B      = in_sizes[0] / MC;      // 256
    const int max_dc = in_sizes[4] / MC;

    setup_all<<<1, BLOCK, 0, stream>>>(check_mask, check_adj, var_adj, max_dc, ws);
    bp_decode<<<B, BLOCK, 0, stream>>>(syndrome, llr, ws, out, B);
}